// Round 1
// baseline (169.465 us; speedup 1.0000x reference)
//
#include <hip/hip_runtime.h>

// MMD loss, fused. ws layout (needs ~2.2 MB):
//   [0,16)    double sums[2]  : {S_same, S_all}
//   [16,80)   int    hist[16] : domain histogram
//   [128, 128+4N)           float sq[N]      (exact fp32 row norms)
//   [128+4N, 128+4N+2*N*D)  ushort fbf[N*D]  (bf16 feature, RNE)

typedef __attribute__((ext_vector_type(8))) short short8;
typedef __attribute__((ext_vector_type(4))) float floatx4;

__device__ inline unsigned short f2bf(float f) {
  union { float f; unsigned u; } v; v.f = f;
  unsigned u = v.u;
  unsigned r = u + 0x7fffu + ((u >> 16) & 1u);   // round-to-nearest-even
  return (unsigned short)(r >> 16);
}

__device__ inline float fast_exp2(float x) {
#if __has_builtin(__builtin_amdgcn_exp2f)
  return __builtin_amdgcn_exp2f(x);
#else
  return exp2f(x);
#endif
}

__global__ __launch_bounds__(256) void prep_kernel(
    const float* __restrict__ feat, const int* __restrict__ dom,
    unsigned short* __restrict__ fbf, float* __restrict__ sq,
    int* __restrict__ hist, int N, int D) {
  int row  = blockIdx.x * 4 + (threadIdx.x >> 6);
  int lane = threadIdx.x & 63;
  if (row >= N) return;
  const float4* src = (const float4*)(feat + (size_t)row * D);
  ushort4* dst = (ushort4*)(fbf + (size_t)row * D);
  float ss = 0.f;
  for (int c = lane; c < (D >> 2); c += 64) {
    float4 v = src[c];
    ss += v.x * v.x + v.y * v.y + v.z * v.z + v.w * v.w;
    ushort4 o;
    o.x = f2bf(v.x); o.y = f2bf(v.y); o.z = f2bf(v.z); o.w = f2bf(v.w);
    dst[c] = o;
  }
  #pragma unroll
  for (int off = 32; off > 0; off >>= 1) ss += __shfl_down(ss, off);
  if (lane == 0) {
    sq[row] = ss;
    atomicAdd(&hist[dom[row] & 15], 1);
  }
}

// Triangle-tiled fused kernel: 64x64 tile per block, 256 threads = 4 waves.
// Wave w owns rows [w*16, w*16+16) of the tile, all 64 cols (4 MFMA n-tiles).
__global__ __launch_bounds__(256) void mmd_main(
    const unsigned short* __restrict__ fbf, const float* __restrict__ sq,
    const int* __restrict__ dom, double* __restrict__ sums, int N, int D) {
  const int ti = blockIdx.y, tj = blockIdx.x;
  if (ti > tj) return;                 // symmetric: upper triangle only
  const int rowI = ti * 64, rowJ = tj * 64;

  __shared__ __align__(16) unsigned short As[64 * 64];   // [row][k], k-stride 64
  __shared__ __align__(16) unsigned short Bs[64 * 64];
  __shared__ float sqI[64], sqJ[64];
  __shared__ int   dmI[64], dmJ[64];
  __shared__ float red[8];

  const int tid = threadIdx.x;
  if (tid < 64)       { sqI[tid] = sq[rowI + tid];      dmI[tid] = dom[rowI + tid]; }
  else if (tid < 128) { int t = tid - 64; sqJ[t] = sq[rowJ + t]; dmJ[t] = dom[rowJ + t]; }

  const int lane = tid & 63, w = tid >> 6;
  const int quad = lane >> 4, m16 = lane & 15;

  floatx4 acc[4];
  #pragma unroll
  for (int t = 0; t < 4; ++t) acc[t] = (floatx4){0.f, 0.f, 0.f, 0.f};

  for (int kb = 0; kb < D; kb += 64) {
    __syncthreads();   // previous-iter LDS reads done (1st iter: sq/dm visible)
    // stage A and B 64x64 bf16 tiles: 512 16B-chunks each, 2 per thread
    for (int ch = tid; ch < 512; ch += 256) {
      int row = ch >> 3;
      int kc  = (ch & 7) << 3;
      ((uint4*)As)[ch] = *(const uint4*)(fbf + (size_t)(rowI + row) * D + kb + kc);
      ((uint4*)Bs)[ch] = *(const uint4*)(fbf + (size_t)(rowJ + row) * D + kb + kc);
    }
    __syncthreads();
    #pragma unroll
    for (int ks = 0; ks < 64; ks += 32) {
      short8 a = *(const short8*)(As + (w * 16 + m16) * 64 + ks + quad * 8);
      #pragma unroll
      for (int t = 0; t < 4; ++t) {
        short8 b = *(const short8*)(Bs + (t * 16 + m16) * 64 + ks + quad * 8);
        acc[t] = __builtin_amdgcn_mfma_f32_16x16x32_bf16(a, b, acc[t], 0, 0, 0);
      }
    }
  }

  // -0.5 * sigma * log2(e) for the 12 sigmas
  const float NEGC[12] = {
    -7.2134752e-05f, -7.2134752e-04f, -7.2134752e-03f, -7.2134752e-02f,
    -0.72134752f,    -3.6067376f,     -7.2134752f,     -10.82021281f,
    -14.42695041f,   -18.03368801f,   -21.64042561f,   -72.13475204f };

  float s_all = 0.f, s_same = 0.f;
  #pragma unroll
  for (int t = 0; t < 4; ++t) {
    const int c = t * 16 + m16;          // C/D: col = lane&15
    const float sqc = sqJ[c];
    const int dc = dmJ[c];
    const int gj = rowJ + c;
    #pragma unroll
    for (int reg = 0; reg < 4; ++reg) {
      const int r = w * 16 + quad * 4 + reg;   // C/D: row = quad*4 + reg
      const int gi = rowI + r;
      float d2 = sqI[r] + sqc - 2.f * acc[t][reg];
      d2 = fmaxf(d2, 0.f);
      if (gi == gj) d2 = 0.f;            // diagonal exact: k = 12 (dominates answer)
      float kk = 0.f;
      #pragma unroll
      for (int s = 0; s < 12; ++s) kk += fast_exp2(d2 * NEGC[s]);
      s_all += kk;
      if (dmI[r] == dc) s_same += kk;
    }
  }
  #pragma unroll
  for (int off = 32; off > 0; off >>= 1) {
    s_all  += __shfl_down(s_all, off);
    s_same += __shfl_down(s_same, off);
  }
  if (lane == 0) { red[w] = s_all; red[4 + w] = s_same; }
  __syncthreads();
  if (tid == 0) {
    const float wt = (ti == tj) ? 1.f : 2.f;   // off-diag tiles count twice
    float a = (red[0] + red[1] + red[2] + red[3]) * wt;
    float s = (red[4] + red[5] + red[6] + red[7]) * wt;
    atomicAdd(&sums[0], (double)s);
    atomicAdd(&sums[1], (double)a);
  }
}

__global__ void finalize_kernel(const double* __restrict__ sums,
                                const int* __restrict__ hist,
                                float* __restrict__ out, int N) {
  double csame = 0.0;
  for (int i = 0; i < 16; ++i) { double h = (double)hist[i]; csame += h * h; }
  double call = (double)N * (double)N;
  double Ex = sums[0] / csame;
  double Ey = (sums[1] - sums[0]) / (call - csame);
  out[0] = (float)(Ex - Ey);
}

extern "C" void kernel_launch(void* const* d_in, const int* in_sizes, int n_in,
                              void* d_out, int out_size, void* d_ws, size_t ws_size,
                              hipStream_t stream) {
  const float* feat = (const float*)d_in[0];
  const int* dom = (const int*)d_in[1];
  float* out = (float*)d_out;
  const int N = in_sizes[1];
  const int D = in_sizes[0] / N;

  char* ws = (char*)d_ws;
  double* sums = (double*)ws;                               // 16 B
  int* hist = (int*)(ws + 16);                              // 64 B
  float* sq = (float*)(ws + 128);                           // 4N B
  unsigned short* fbf = (unsigned short*)(ws + 128 + 4 * (size_t)N);  // 2*N*D B

  hipMemsetAsync(d_ws, 0, 128, stream);                     // zero sums + hist
  prep_kernel<<<dim3((N + 3) / 4), dim3(256), 0, stream>>>(feat, dom, fbf, sq, hist, N, D);
  mmd_main<<<dim3(N / 64, N / 64), dim3(256), 0, stream>>>(fbf, sq, dom, sums, N, D);
  finalize_kernel<<<1, 1, 0, stream>>>(sums, hist, out, N);
}

// Round 2
// 144.447 us; speedup vs baseline: 1.1732x; 1.1732x over previous
//
#include <hip/hip_runtime.h>

// MMD loss. ws layout:
//   [0,16)    double sums[2] : {S_same, S_all}
//   [16,80)   int hist[16]
//   [128, 128+4N)  float sq[N]
//   [128+4N, ...)  uint4 fbt[N*D/8]  bf16 feature, TILED k-major:
//        chunk (rt, kc, r) -> index rt*(D/8)*64 + kc*64 + r   (16B chunks)
//        holds feature[rt*64 + r][kc*8 .. kc*8+8) as bf16

typedef __attribute__((ext_vector_type(8))) short short8;
typedef __attribute__((ext_vector_type(4))) float floatx4;

#define AS1 __attribute__((address_space(1)))
#define AS3 __attribute__((address_space(3)))

__device__ inline unsigned f2bf2(float lo, float hi) {
  union { float f; unsigned u; } a, b; a.f = lo; b.f = hi;
  unsigned ra = (a.u + 0x7fffu + ((a.u >> 16) & 1u)) >> 16;
  unsigned rb = (b.u + 0x7fffu + ((b.u >> 16) & 1u)) >> 16;
  return ra | (rb << 16);
}

__device__ inline float fast_exp2(float x) {
#if __has_builtin(__builtin_amdgcn_exp2f)
  return __builtin_amdgcn_exp2f(x);
#else
  return exp2f(x);
#endif
}

// 8 rows per block; thread (r8 = tid>>5, kc = tid&31) converts one 16B chunk.
__global__ __launch_bounds__(256) void prep_kernel(
    const float* __restrict__ feat, const int* __restrict__ dom,
    uint4* __restrict__ fbt, float* __restrict__ sq,
    int* __restrict__ hist, int N, int D) {
  const int tid = threadIdx.x;
  const int row = blockIdx.x * 8 + (tid >> 5);
  const int kc = tid & 31;                      // D/8 = 32 chunks
  if (row >= N) return;
  const float4* src = (const float4*)(feat + (size_t)row * D) + kc * 2;
  float4 v0 = src[0], v1 = src[1];
  float ss = v0.x*v0.x + v0.y*v0.y + v0.z*v0.z + v0.w*v0.w
           + v1.x*v1.x + v1.y*v1.y + v1.z*v1.z + v1.w*v1.w;
  uint4 o;
  o.x = f2bf2(v0.x, v0.y); o.y = f2bf2(v0.z, v0.w);
  o.z = f2bf2(v1.x, v1.y); o.w = f2bf2(v1.z, v1.w);
  const int nkc = D >> 3;
  fbt[(size_t)(row >> 6) * nkc * 64 + kc * 64 + (row & 63)] = o;
  #pragma unroll
  for (int off = 16; off > 0; off >>= 1) ss += __shfl_down(ss, off, 32);
  if (kc == 0) {
    sq[row] = ss;
    atomicAdd(&hist[dom[row] & 15], 1);
  }
}

// One 64x64 tile pair per block (upper triangle only), 256 thr = 4 waves.
// A fragments in regs (8 x short8); B tile staged once: 32KB LDS, 1 barrier.
__global__ __launch_bounds__(256) void mmd_main(
    const uint4* __restrict__ fbt, const float* __restrict__ sq,
    const int* __restrict__ dom, double* __restrict__ sums, int N) {
  // triangle decode: (ti <= tj)
  int b = blockIdx.x;
  int i = (int)((sqrtf(8.f * (float)b + 1.f) - 1.f) * 0.5f);
  while ((i + 1) * (i + 2) / 2 <= b) ++i;
  while (i * (i + 1) / 2 > b) --i;
  const int ti = b - i * (i + 1) / 2;
  const int tj = i;
  const int rowI = ti * 64, rowJ = tj * 64;

  __shared__ __align__(16) uint4 Bs[2048];      // 32 KB: chunk (kc, r) = kc*64+r
  __shared__ float sqI[64], sqJ[64];
  __shared__ int dmI[64], dmJ[64];
  __shared__ float red[8];

  const int tid = threadIdx.x;
  const int lane = tid & 63, w = tid >> 6;
  const int quad = lane >> 4, m16 = lane & 15;

  const uint4* At = fbt + (size_t)ti * 2048;
  const uint4* Bt = fbt + (size_t)tj * 2048;

  // stage B: 8 x (wave-contiguous 1KB) direct global->LDS
  #pragma unroll
  for (int p = 0; p < 8; ++p) {
    const int base = w * 64 + p * 256;
#if __has_builtin(__builtin_amdgcn_global_load_lds)
    __builtin_amdgcn_global_load_lds(
        (const AS1 uint4*)(Bt + base + lane),
        (AS3 uint4*)(Bs + base), 16, 0, 0);
#else
    Bs[base + lane] = Bt[base + lane];
#endif
  }

  // A fragments straight to registers: slab s covers k [s*32, s*32+32)
  short8 afrag[8];
  #pragma unroll
  for (int s = 0; s < 8; ++s) {
    uint4 t = At[(s * 4 + quad) * 64 + w * 16 + m16];
    afrag[s] = *(short8*)&t;
  }

  if (tid < 64)       { sqI[tid] = sq[rowI + tid];      dmI[tid] = dom[rowI + tid]; }
  else if (tid < 128) { int t = tid - 64; sqJ[t] = sq[rowJ + t]; dmJ[t] = dom[rowJ + t]; }
  __syncthreads();   // drains global_load_lds (vmcnt) + sq/dm visible

  floatx4 acc[4];
  #pragma unroll
  for (int t = 0; t < 4; ++t) acc[t] = (floatx4){0.f, 0.f, 0.f, 0.f};

  const unsigned short* BsS = (const unsigned short*)Bs;
  #pragma unroll
  for (int s = 0; s < 8; ++s) {
    #pragma unroll
    for (int t = 0; t < 4; ++t) {
      short8 bf = *(const short8*)(BsS + ((size_t)((s * 4 + quad) * 64 + t * 16 + m16)) * 8);
      acc[t] = __builtin_amdgcn_mfma_f32_16x16x32_bf16(afrag[s], bf, acc[t], 0, 0, 0);
    }
  }

  const float NEGC[12] = {
    -7.2134752e-05f, -7.2134752e-04f, -7.2134752e-03f, -7.2134752e-02f,
    -0.72134752f,    -3.6067376f,     -7.2134752f,     -10.82021281f,
    -14.42695041f,   -18.03368801f,   -21.64042561f,   -72.13475204f };

  float s_all = 0.f, s_same = 0.f;
  #pragma unroll
  for (int t = 0; t < 4; ++t) {
    const int c = t * 16 + m16;                 // C/D: col = lane&15
    const float sqc = sqJ[c];
    const int dc = dmJ[c];
    const int gj = rowJ + c;
    #pragma unroll
    for (int reg = 0; reg < 4; ++reg) {
      const int r = w * 16 + quad * 4 + reg;    // C/D: row = quad*4 + reg
      const int gi = rowI + r;
      float d2 = sqI[r] + sqc - 2.f * acc[t][reg];
      d2 = fmaxf(d2, 0.f);
      if (gi == gj) d2 = 0.f;                   // diagonal exact: k=12 dominates
      float kk = 0.f;
      #pragma unroll
      for (int s = 0; s < 12; ++s) kk += fast_exp2(d2 * NEGC[s]);
      s_all += kk;
      if (dmI[r] == dc) s_same += kk;
    }
  }
  #pragma unroll
  for (int off = 32; off > 0; off >>= 1) {
    s_all  += __shfl_down(s_all, off);
    s_same += __shfl_down(s_same, off);
  }
  if (lane == 0) { red[w] = s_all; red[4 + w] = s_same; }
  __syncthreads();
  if (tid == 0) {
    const float wt = (ti == tj) ? 1.f : 2.f;    // off-diag tiles count twice
    float a = (red[0] + red[1] + red[2] + red[3]) * wt;
    float s = (red[4] + red[5] + red[6] + red[7]) * wt;
    atomicAdd(&sums[0], (double)s);
    atomicAdd(&sums[1], (double)a);
  }
}

__global__ void finalize_kernel(const double* __restrict__ sums,
                                const int* __restrict__ hist,
                                float* __restrict__ out, int N) {
  double csame = 0.0;
  for (int i = 0; i < 16; ++i) { double h = (double)hist[i]; csame += h * h; }
  double call = (double)N * (double)N;
  double Ex = sums[0] / csame;
  double Ey = (sums[1] - sums[0]) / (call - csame);
  out[0] = (float)(Ex - Ey);
}

extern "C" void kernel_launch(void* const* d_in, const int* in_sizes, int n_in,
                              void* d_out, int out_size, void* d_ws, size_t ws_size,
                              hipStream_t stream) {
  const float* feat = (const float*)d_in[0];
  const int* dom = (const int*)d_in[1];
  float* out = (float*)d_out;
  const int N = in_sizes[1];
  const int D = in_sizes[0] / N;

  char* ws = (char*)d_ws;
  double* sums = (double*)ws;                              // 16 B
  int* hist = (int*)(ws + 16);                             // 64 B
  float* sq = (float*)(ws + 128);                          // 4N B
  uint4* fbt = (uint4*)(ws + 128 + 4 * (size_t)N);         // 2*N*D B (16-aligned)

  hipMemsetAsync(d_ws, 0, 128, stream);
  prep_kernel<<<dim3(N / 8), dim3(256), 0, stream>>>(feat, dom, fbt, sq, hist, N, D);
  const int T = N / 64;
  mmd_main<<<dim3(T * (T + 1) / 2), dim3(256), 0, stream>>>(fbt, sq, dom, sums, N);
  finalize_kernel<<<1, 1, 0, stream>>>(sums, hist, out, N);
}

// Round 3
// 81.446 us; speedup vs baseline: 2.0807x; 1.7735x over previous
//
#include <hip/hip_runtime.h>

// MMD loss, atomic-free. ws layout (~2.08 MB):
//   [0, 16640)        float2 partial[2080]   per-block {S_same, S_all}
//   [16640, 82176)    float  sqpart[4][N]    row-norm partials (one per k-quarter)
//   [82176, +2*N*D)   uint4  fbt[N*D/8]      bf16 feature, TILED k-major:
//        chunk (rt, kc, r) -> index rt*(D/8)*64 + kc*64 + r   (16B chunks)
//        holds feature[rt*64 + r][kc*8 .. kc*8+8) as bf16

typedef __attribute__((ext_vector_type(8))) short short8;
typedef __attribute__((ext_vector_type(4))) float floatx4;

#define AS1 __attribute__((address_space(1)))
#define AS3 __attribute__((address_space(3)))

__device__ inline unsigned f2bf2(float lo, float hi) {
  union { float f; unsigned u; } a, b; a.f = lo; b.f = hi;
  unsigned ra = (a.u + 0x7fffu + ((a.u >> 16) & 1u)) >> 16;
  unsigned rb = (b.u + 0x7fffu + ((b.u >> 16) & 1u)) >> 16;
  return ra | (rb << 16);
}

__device__ inline float fast_exp2(float x) {
#if __has_builtin(__builtin_amdgcn_exp2f)
  return __builtin_amdgcn_exp2f(x);
#else
  return exp2f(x);
#endif
}

// Grid: (N/64)*4 blocks. Block = (rt = bid>>2, kq = bid&3) covers rows
// [rt*64, rt*64+64) x cols [kq*64, kq*64+64). Coalesced fbt writes
// (wave = 64 consecutive chunks). No atomics; row-norm partial per kq.
__global__ __launch_bounds__(256) void prep_kernel(
    const float* __restrict__ feat, uint4* __restrict__ fbt,
    float* __restrict__ sqpart, int N, int D) {
  const int tid = threadIdx.x;
  const int rt = blockIdx.x >> 2;
  const int kq = blockIdx.x & 3;
  const int r = tid & 63;
  const int nkc = D >> 3;                     // 32 chunks of 8 cols
  __shared__ float sqp[256];
  float ss = 0.f;
  #pragma unroll
  for (int it = 0; it < 2; ++it) {
    const int kc = kq * 8 + it * 4 + (tid >> 6);
    const float4* src = (const float4*)(feat + (size_t)(rt * 64 + r) * D + kc * 8);
    float4 v0 = src[0], v1 = src[1];
    ss += v0.x*v0.x + v0.y*v0.y + v0.z*v0.z + v0.w*v0.w
        + v1.x*v1.x + v1.y*v1.y + v1.z*v1.z + v1.w*v1.w;
    uint4 o;
    o.x = f2bf2(v0.x, v0.y); o.y = f2bf2(v0.z, v0.w);
    o.z = f2bf2(v1.x, v1.y); o.w = f2bf2(v1.z, v1.w);
    fbt[(size_t)rt * nkc * 64 + kc * 64 + r] = o;
  }
  sqp[tid] = ss;
  __syncthreads();
  if (tid < 64)
    sqpart[(size_t)kq * N + rt * 64 + tid] =
        sqp[tid] + sqp[tid + 64] + sqp[tid + 128] + sqp[tid + 192];
}

// One 64x64 tile pair per block (upper triangle), 256 thr = 4 waves.
// A frags in regs; B staged once via global_load_lds; one barrier; no atomics.
__global__ __launch_bounds__(256) void mmd_main(
    const uint4* __restrict__ fbt, const float* __restrict__ sqpart,
    const int* __restrict__ dom, float2* __restrict__ partial, int N) {
  int b = blockIdx.x;
  int i = (int)((sqrtf(8.f * (float)b + 1.f) - 1.f) * 0.5f);
  while ((i + 1) * (i + 2) / 2 <= b) ++i;
  while (i * (i + 1) / 2 > b) --i;
  const int ti = b - i * (i + 1) / 2;
  const int tj = i;
  const int rowI = ti * 64, rowJ = tj * 64;

  __shared__ __align__(16) uint4 Bs[2048];    // 32 KB: chunk (kc, r) = kc*64+r
  __shared__ float sqI[64], sqJ[64];
  __shared__ int dmI[64], dmJ[64];
  __shared__ float red[8];

  const int tid = threadIdx.x;
  const int lane = tid & 63, w = tid >> 6;
  const int quad = lane >> 4, m16 = lane & 15;

  const uint4* At = fbt + (size_t)ti * 2048;
  const uint4* Bt = fbt + (size_t)tj * 2048;

  #pragma unroll
  for (int p = 0; p < 8; ++p) {
    const int base = w * 64 + p * 256;
#if __has_builtin(__builtin_amdgcn_global_load_lds)
    __builtin_amdgcn_global_load_lds(
        (const AS1 uint4*)(Bt + base + lane),
        (AS3 uint4*)(Bs + base), 16, 0, 0);
#else
    Bs[base + lane] = Bt[base + lane];
#endif
  }

  short8 afrag[8];
  #pragma unroll
  for (int s = 0; s < 8; ++s) {
    uint4 t = At[(s * 4 + quad) * 64 + w * 16 + m16];
    afrag[s] = *(short8*)&t;
  }

  if (tid < 64) {
    sqI[tid] = sqpart[rowI + tid] + sqpart[N + rowI + tid]
             + sqpart[2 * N + rowI + tid] + sqpart[3 * N + rowI + tid];
    dmI[tid] = dom[rowI + tid];
  } else if (tid < 128) {
    int t = tid - 64;
    sqJ[t] = sqpart[rowJ + t] + sqpart[N + rowJ + t]
           + sqpart[2 * N + rowJ + t] + sqpart[3 * N + rowJ + t];
    dmJ[t] = dom[rowJ + t];
  }
  __syncthreads();   // drains global_load_lds + sq/dm visible

  floatx4 acc[4];
  #pragma unroll
  for (int t = 0; t < 4; ++t) acc[t] = (floatx4){0.f, 0.f, 0.f, 0.f};

  const unsigned short* BsS = (const unsigned short*)Bs;
  #pragma unroll
  for (int s = 0; s < 8; ++s) {
    #pragma unroll
    for (int t = 0; t < 4; ++t) {
      short8 bf = *(const short8*)(BsS + ((size_t)((s * 4 + quad) * 64 + t * 16 + m16)) * 8);
      acc[t] = __builtin_amdgcn_mfma_f32_16x16x32_bf16(afrag[s], bf, acc[t], 0, 0, 0);
    }
  }

  // c_s = -0.5*log2(e)*sigma for sigma in {1e-4,1e-3,1e-2,0.1,1,5,100};
  // sigma 10..30 built from powers of the sigma=5 term.
  const float C0 = -7.2134752e-05f, C1 = -7.2134752e-04f, C2 = -7.2134752e-03f,
              C3 = -7.2134752e-02f, C4 = -0.72134752f, C5 = -3.6067376f,
              C100 = -72.13475204f;

  float s_all = 0.f, s_same = 0.f;
  #pragma unroll
  for (int t = 0; t < 4; ++t) {
    const int c = t * 16 + m16;                // C/D: col = lane&15
    const float sqc = sqJ[c];
    const int dc = dmJ[c];
    const int gj = rowJ + c;
    #pragma unroll
    for (int reg = 0; reg < 4; ++reg) {
      const int r = w * 16 + quad * 4 + reg;   // C/D: row = quad*4 + reg
      const int gi = rowI + r;
      float d2 = sqI[r] + sqc - 2.f * acc[t][reg];
      d2 = fmaxf(d2, 0.f);
      if (gi == gj) d2 = 0.f;                  // diagonal exact: k=12 dominates
      float e0 = fast_exp2(d2 * C0), e1 = fast_exp2(d2 * C1);
      float e2 = fast_exp2(d2 * C2), e3 = fast_exp2(d2 * C3);
      float e4 = fast_exp2(d2 * C4), e5 = fast_exp2(d2 * C5);
      float e11 = fast_exp2(d2 * C100);
      float t10 = e5 * e5, t15 = t10 * e5, t20 = t10 * t10;
      float t25 = t15 * t10, t30 = t15 * t15;
      float kk = ((e0 + e1) + (e2 + e3)) + ((e4 + e5) + (t10 + t15))
               + ((t20 + t25) + (t30 + e11));
      s_all += kk;
      if (dmI[r] == dc) s_same += kk;
    }
  }
  #pragma unroll
  for (int off = 32; off > 0; off >>= 1) {
    s_all  += __shfl_down(s_all, off);
    s_same += __shfl_down(s_same, off);
  }
  if (lane == 0) { red[w] = s_all; red[4 + w] = s_same; }
  __syncthreads();
  if (tid == 0) {
    const float wt = (ti == tj) ? 1.f : 2.f;   // off-diag tiles count twice
    float a = (red[0] + red[1] + red[2] + red[3]) * wt;
    float s = (red[4] + red[5] + red[6] + red[7]) * wt;
    partial[b] = make_float2(s, a);
  }
}

__global__ __launch_bounds__(256) void finalize_kernel(
    const float2* __restrict__ partial, int nblk,
    const int* __restrict__ dom, float* __restrict__ out, int N) {
  __shared__ int histL[16];
  __shared__ double redS[8];
  const int tid = threadIdx.x;
  if (tid < 16) histL[tid] = 0;
  __syncthreads();
  for (int i = tid; i < N; i += 256) atomicAdd(&histL[dom[i] & 15], 1);
  double as = 0.0, aa = 0.0;
  for (int i = tid; i < nblk; i += 256) {
    float2 p = partial[i];
    as += (double)p.x; aa += (double)p.y;
  }
  #pragma unroll
  for (int off = 32; off > 0; off >>= 1) {
    as += __shfl_down(as, off);
    aa += __shfl_down(aa, off);
  }
  const int w = tid >> 6;
  if ((tid & 63) == 0) { redS[w] = as; redS[4 + w] = aa; }
  __syncthreads();
  if (tid == 0) {
    double S = redS[0] + redS[1] + redS[2] + redS[3];
    double A = redS[4] + redS[5] + redS[6] + redS[7];
    double csame = 0.0;
    for (int i = 0; i < 16; ++i) { double h = (double)histL[i]; csame += h * h; }
    double call = (double)N * (double)N;
    out[0] = (float)(S / csame - (A - S) / (call - csame));
  }
}

extern "C" void kernel_launch(void* const* d_in, const int* in_sizes, int n_in,
                              void* d_out, int out_size, void* d_ws, size_t ws_size,
                              hipStream_t stream) {
  const float* feat = (const float*)d_in[0];
  const int* dom = (const int*)d_in[1];
  float* out = (float*)d_out;
  const int N = in_sizes[1];
  const int D = in_sizes[0] / N;
  const int T = N / 64;
  const int nblk = T * (T + 1) / 2;

  char* ws = (char*)d_ws;
  float2* partial = (float2*)ws;                       // 8*nblk = 16640 B
  float* sqpart = (float*)(ws + 16640);                // 4*N floats = 65536 B
  uint4* fbt = (uint4*)(ws + 82176);                   // 2*N*D B, 16-aligned

  prep_kernel<<<dim3(T * 4), dim3(256), 0, stream>>>(feat, fbt, sqpart, N, D);
  mmd_main<<<dim3(nblk), dim3(256), 0, stream>>>(fbt, sqpart, dom, partial, N);
  finalize_kernel<<<1, 256, 0, stream>>>(partial, nblk, dom, out, N);
}